// Round 1
// baseline (236.104 us; speedup 1.0000x reference)
//
#include <hip/hip_runtime.h>
#include <hip/hip_bf16.h>

#define NB 8
#define BIN 512
#define BOUT 512
#define BATCH 8192
#define DIM 4096   // NB*BIN

typedef __attribute__((ext_vector_type(8))) short bf16x8;
typedef __attribute__((ext_vector_type(4))) float f32x4;

__device__ __forceinline__ unsigned short f2bf_rne(float f) {
    unsigned u = __builtin_bit_cast(unsigned, f);
    unsigned r = (u + 0x7FFFu + ((u >> 16) & 1u)) >> 16;
    return (unsigned short)r;
}

// ---------------- weight conversion: f32 -> bf16 ----------------
__global__ void cvt_f32_bf16(const float* __restrict__ in,
                             unsigned short* __restrict__ out, int n4) {
    int i = blockIdx.x * blockDim.x + threadIdx.x;
    if (i >= n4) return;
    f32x4 v = *(const f32x4*)(in + (size_t)i * 4);
    unsigned long long p =  (unsigned long long)f2bf_rne(v.x)
        | ((unsigned long long)f2bf_rne(v.y) << 16)
        | ((unsigned long long)f2bf_rne(v.z) << 32)
        | ((unsigned long long)f2bf_rne(v.w) << 48);
    *(unsigned long long*)(out + (size_t)i * 4) = p;
}

// ---------------- block-diag GEMM ----------------
// C[r][c] = relu( sum_k A[r][k] * W[c][k] + bias[c] )   (per diagonal block)
// Tile: 128(M) x 128(N), BK=64, 256 threads = 4 waves in 2x2 wave grid.
// LDS tiles XOR-swizzled: byte ^= ((row&7)<<4) to balance ds_read_b128 banks.
template<bool A_IS_F32, bool OUT_BF16>
__global__ __launch_bounds__(256, 2)
void bdgemm(const void* __restrict__ Aptr,            // [8192][4096] f32 or bf16
            const unsigned short* __restrict__ Bw,    // [NB*BOUT][BIN] bf16
            const float* __restrict__ bias,           // [4096] f32
            void* __restrict__ Out)                   // [8192][4096] bf16 or f32
{
    __shared__ __align__(16) unsigned char As[128 * 64 * 2];
    __shared__ __align__(16) unsigned char Bs[128 * 64 * 2];

    const int bid = blockIdx.x;
    const int nb  = bid >> 8;          // 8 diag blocks; 256 tiles each (64 mt x 4 nt)
    const int rem = bid & 255;
    const int mt  = rem >> 2;
    const int nt  = rem & 3;

    const int t    = threadIdx.x;
    const int wid  = t >> 6;
    const int lane = t & 63;
    const int wm   = wid >> 1;
    const int wn   = wid & 1;

    const int row0   = mt * 128;              // global row base
    const int colA0  = nb * 512;              // A column (k) base
    const int wrow0  = nb * 512 + nt * 128;   // weight-row / out-col base

    f32x4 acc[4][4];
    #pragma unroll
    for (int i = 0; i < 4; i++)
        #pragma unroll
        for (int j = 0; j < 4; j++)
            acc[i][j] = (f32x4)(0.f);

    for (int kt = 0; kt < BIN; kt += 64) {
        // ---- stage A tile [128][64] ----
        if (A_IS_F32) {
            const float* A = (const float*)Aptr;
            #pragma unroll
            for (int i = 0; i < 8; i++) {
                int e = i * 1024 + t * 4;
                int r = e >> 6, c = e & 63;
                f32x4 v = *(const f32x4*)(A + (size_t)(row0 + r) * DIM + colA0 + kt + c);
                unsigned long long p =  (unsigned long long)f2bf_rne(v.x)
                    | ((unsigned long long)f2bf_rne(v.y) << 16)
                    | ((unsigned long long)f2bf_rne(v.z) << 32)
                    | ((unsigned long long)f2bf_rne(v.w) << 48);
                int byte = r * 128 + ((c * 2) ^ ((r & 7) << 4));
                *(unsigned long long*)(As + byte) = p;
            }
        } else {
            const unsigned short* A = (const unsigned short*)Aptr;
            #pragma unroll
            for (int i = 0; i < 4; i++) {
                int e = i * 2048 + t * 8;
                int r = e >> 6, c = e & 63;
                bf16x8 v = *(const bf16x8*)(A + (size_t)(row0 + r) * DIM + colA0 + kt + c);
                int byte = r * 128 + ((c * 2) ^ ((r & 7) << 4));
                *(bf16x8*)(As + byte) = v;
            }
        }
        // ---- stage B (weight) tile [128][64] ----
        #pragma unroll
        for (int i = 0; i < 4; i++) {
            int e = i * 2048 + t * 8;
            int r = e >> 6, c = e & 63;
            bf16x8 v = *(const bf16x8*)(Bw + (size_t)(wrow0 + r) * BIN + kt + c);
            int byte = r * 128 + ((c * 2) ^ ((r & 7) << 4));
            *(bf16x8*)(Bs + byte) = v;
        }
        __syncthreads();

        // ---- MFMA over BK=64 (two K=32 sub-steps) ----
        #pragma unroll
        for (int ks = 0; ks < 2; ks++) {
            bf16x8 af[4], bfr[4];
            const int cbyte = (ks * 32 + (lane >> 4) * 8) * 2;
            #pragma unroll
            for (int m = 0; m < 4; m++) {
                int r = wm * 64 + m * 16 + (lane & 15);
                af[m] = *(const bf16x8*)(As + r * 128 + (cbyte ^ ((r & 7) << 4)));
            }
            #pragma unroll
            for (int n = 0; n < 4; n++) {
                int r = wn * 64 + n * 16 + (lane & 15);
                bfr[n] = *(const bf16x8*)(Bs + r * 128 + (cbyte ^ ((r & 7) << 4)));
            }
            #pragma unroll
            for (int m = 0; m < 4; m++)
                #pragma unroll
                for (int n = 0; n < 4; n++)
                    acc[m][n] = __builtin_amdgcn_mfma_f32_16x16x32_bf16(
                        af[m], bfr[n], acc[m][n], 0, 0, 0);
        }
        __syncthreads();
    }

    // ---- epilogue: +bias, relu, store ----
    const int lr = lane >> 4, lc = lane & 15;
    #pragma unroll
    for (int n = 0; n < 4; n++) {
        int col = wrow0 + wn * 64 + n * 16 + lc;   // global out column
        float bv = bias[col];
        #pragma unroll
        for (int m = 0; m < 4; m++) {
            int rbase = row0 + wm * 64 + m * 16 + lr * 4;
            #pragma unroll
            for (int r = 0; r < 4; r++) {
                float v = acc[m][n][r] + bv;
                v = v > 0.f ? v : 0.f;
                if (OUT_BF16)
                    ((unsigned short*)Out)[(size_t)(rbase + r) * DIM + col] = f2bf_rne(v);
                else
                    ((float*)Out)[(size_t)(rbase + r) * DIM + col] = v;
            }
        }
    }
}

extern "C" void kernel_launch(void* const* d_in, const int* in_sizes, int n_in,
                              void* d_out, int out_size, void* d_ws, size_t ws_size,
                              hipStream_t stream) {
    const float* x  = (const float*)d_in[0];
    const float* W1 = (const float*)d_in[1];
    const float* b1 = (const float*)d_in[2];
    const float* W2 = (const float*)d_in[3];
    const float* b2 = (const float*)d_in[4];
    float* out = (float*)d_out;

    char* ws = (char*)d_ws;
    unsigned short* W1bf = (unsigned short*)ws;                    // 4 MB
    unsigned short* W2bf = (unsigned short*)(ws + (4u << 20));     // 4 MB
    unsigned short* hbf  = (unsigned short*)(ws + (8u << 20));     // 64 MB

    const int WELEM = NB * BOUT * BIN;          // 2,097,152 per weight tensor
    cvt_f32_bf16<<<(WELEM / 4 + 255) / 256, 256, 0, stream>>>(W1, W1bf, WELEM / 4);
    cvt_f32_bf16<<<(WELEM / 4 + 255) / 256, 256, 0, stream>>>(W2, W2bf, WELEM / 4);

    const int GRID = NB * (BATCH / 128) * (BOUT / 128);   // 8*64*4 = 2048
    bdgemm<true,  true ><<<GRID, 256, 0, stream>>>(x,   W1bf, b1, hbf);
    bdgemm<false, false><<<GRID, 256, 0, stream>>>(hbf, W2bf, b2, out);
}

// Round 2
// 135.451 us; speedup vs baseline: 1.7431x; 1.7431x over previous
//
#include <hip/hip_runtime.h>
#include <hip/hip_bf16.h>

#define NB 8
#define BIN 512
#define BOUT 512
#define BATCH 8192
#define DIM 4096   // NB*BIN

typedef __attribute__((ext_vector_type(8))) short bf16x8;
typedef __attribute__((ext_vector_type(4))) float f32x4;

#define SWZ(r) (((r) & 7) << 4)

__device__ __forceinline__ unsigned short f2bf_rne(float f) {
    unsigned u = __builtin_bit_cast(unsigned, f);
    unsigned r = (u + 0x7FFFu + ((u >> 16) & 1u)) >> 16;
    return (unsigned short)r;
}

// ---------------- weight conversion: f32 -> bf16 ----------------
__global__ void cvt_f32_bf16(const float* __restrict__ in,
                             unsigned short* __restrict__ out, int n4) {
    int i = blockIdx.x * blockDim.x + threadIdx.x;
    if (i >= n4) return;
    f32x4 v = *(const f32x4*)(in + (size_t)i * 4);
    unsigned long long p =  (unsigned long long)f2bf_rne(v.x)
        | ((unsigned long long)f2bf_rne(v.y) << 16)
        | ((unsigned long long)f2bf_rne(v.z) << 32)
        | ((unsigned long long)f2bf_rne(v.w) << 48);
    *(unsigned long long*)(out + (size_t)i * 4) = p;
}

// ---------------- fused 2-layer block-diag MLP ----------------
// One workgroup: 128 batch rows x one full diagonal block (512 cols), both layers.
// 512 threads = 8 waves in 2(M) x 4(N). Per wave: 64 rows x 128 cols (4x8 frags).
// Phase 1: x(f32->bf16 reg-staged) @ W1 -> relu -> h (bf16) into LDS.
// Phase 2: h(LDS) @ W2 (fragments direct from L2) -> relu -> out (f32). No barriers.
__global__ __launch_bounds__(512, 2)
void fused_mlp(const float* __restrict__ X,
               const unsigned short* __restrict__ W1,
               const float* __restrict__ B1,
               const unsigned short* __restrict__ W2,
               const float* __restrict__ B2,
               float* __restrict__ Out)
{
    __shared__ __align__(16) unsigned char pool[128 * 1024];
    unsigned char* As = pool;            // [128][64] bf16 swizzled, 16 KB (phase 1)
    unsigned char* Bs = pool + 16384;    // [512][64] bf16 swizzled, 64 KB (phase 1)
    unsigned char* Hs = pool;            // [128][512] bf16 swizzled, 128 KB (phase 2)

    const int bid = blockIdx.x;
    const int nb = bid >> 6;      // diagonal block 0..7
    const int mt = bid & 63;      // row tile 0..63

    const int t = threadIdx.x;
    const int lane = t & 63;
    const int wid = t >> 6;
    const int wm = wid >> 2;      // 0..1
    const int wn = wid & 3;       // 0..3

    const int row0 = mt * 128;    // batch-row base
    const int wc0  = nb * 512;    // block base in the 4096-wide dims

    f32x4 acc[4][8];
    #pragma unroll
    for (int m = 0; m < 4; m++)
        #pragma unroll
        for (int n = 0; n < 8; n++)
            acc[m][n] = (f32x4)(0.f);

    // ================= phase 1: h = relu(x @ W1^T + b1) =================
    for (int kt = 0; kt < BIN; kt += 64) {
        // stage A tile [128 rows][64 k], f32 -> bf16
        #pragma unroll
        for (int i = 0; i < 4; i++) {
            int e = i * 2048 + t * 4;
            int r = e >> 6, c = e & 63;
            f32x4 v = *(const f32x4*)(X + (size_t)(row0 + r) * DIM + wc0 + kt + c);
            unsigned long long p =  (unsigned long long)f2bf_rne(v.x)
                | ((unsigned long long)f2bf_rne(v.y) << 16)
                | ((unsigned long long)f2bf_rne(v.z) << 32)
                | ((unsigned long long)f2bf_rne(v.w) << 48);
            *(unsigned long long*)(As + r * 128 + ((c * 2) ^ SWZ(r))) = p;
        }
        // stage B tile [512 w-rows][64 k], bf16
        #pragma unroll
        for (int i = 0; i < 8; i++) {
            int e = i * 4096 + t * 8;
            int r = e >> 6, c = e & 63;
            bf16x8 v = *(const bf16x8*)(W1 + (size_t)(wc0 + r) * BIN + kt + c);
            *(bf16x8*)(Bs + r * 128 + ((c * 2) ^ SWZ(r))) = v;
        }
        __syncthreads();

        #pragma unroll
        for (int ks = 0; ks < 2; ks++) {
            bf16x8 af[4], bfr[8];
            const int cb = (ks * 32 + (lane >> 4) * 8) * 2;
            #pragma unroll
            for (int m = 0; m < 4; m++) {
                int r = wm * 64 + m * 16 + (lane & 15);
                af[m] = *(const bf16x8*)(As + r * 128 + (cb ^ SWZ(r)));
            }
            #pragma unroll
            for (int n = 0; n < 8; n++) {
                int r = wn * 128 + n * 16 + (lane & 15);
                bfr[n] = *(const bf16x8*)(Bs + r * 128 + (cb ^ SWZ(r)));
            }
            #pragma unroll
            for (int m = 0; m < 4; m++)
                #pragma unroll
                for (int n = 0; n < 8; n++)
                    acc[m][n] = __builtin_amdgcn_mfma_f32_16x16x32_bf16(
                        af[m], bfr[n], acc[m][n], 0, 0, 0);
        }
        __syncthreads();
    }

    // write h = relu(acc + b1) into Hs [128][512] bf16 (overlaps As/Bs — dead now)
    #pragma unroll
    for (int n = 0; n < 8; n++) {
        int c = wn * 128 + n * 16 + (lane & 15);        // local h col (= layer-2 k)
        float bv = B1[wc0 + c];
        #pragma unroll
        for (int m = 0; m < 4; m++) {
            int rb = wm * 64 + m * 16 + (lane >> 4) * 4;
            #pragma unroll
            for (int rr = 0; rr < 4; rr++) {
                float v = acc[m][n][rr] + bv;
                v = v > 0.f ? v : 0.f;
                int r = rb + rr;
                *(unsigned short*)(Hs + r * 1024 + ((c * 2) ^ SWZ(r))) = f2bf_rne(v);
            }
        }
    }
    __syncthreads();

    #pragma unroll
    for (int m = 0; m < 4; m++)
        #pragma unroll
        for (int n = 0; n < 8; n++)
            acc[m][n] = (f32x4)(0.f);

    // ================= phase 2: out = relu(h @ W2^T + b2) =================
    // No barriers: h frags from LDS, W2 frags direct from global (L2-resident).
    #pragma unroll 2
    for (int ks = 0; ks < 16; ks++) {
        bf16x8 af[4], bfr[8];
        const int k0 = ks * 32 + (lane >> 4) * 8;
        #pragma unroll
        for (int m = 0; m < 4; m++) {
            int r = wm * 64 + m * 16 + (lane & 15);
            af[m] = *(const bf16x8*)(Hs + r * 1024 + ((k0 * 2) ^ SWZ(r)));
        }
        #pragma unroll
        for (int n = 0; n < 8; n++) {
            int c = wc0 + wn * 128 + n * 16 + (lane & 15);
            bfr[n] = *(const bf16x8*)(W2 + (size_t)c * BIN + k0);
        }
        #pragma unroll
        for (int m = 0; m < 4; m++)
            #pragma unroll
            for (int n = 0; n < 8; n++)
                acc[m][n] = __builtin_amdgcn_mfma_f32_16x16x32_bf16(
                    af[m], bfr[n], acc[m][n], 0, 0, 0);
    }

    // epilogue: out = relu(acc + b2), f32
    #pragma unroll
    for (int n = 0; n < 8; n++) {
        int c = wc0 + wn * 128 + n * 16 + (lane & 15);
        float bv = B2[c];
        #pragma unroll
        for (int m = 0; m < 4; m++) {
            int rb = row0 + wm * 64 + m * 16 + (lane >> 4) * 4;
            #pragma unroll
            for (int rr = 0; rr < 4; rr++) {
                float v = acc[m][n][rr] + bv;
                Out[(size_t)(rb + rr) * DIM + c] = v > 0.f ? v : 0.f;
            }
        }
    }
}

extern "C" void kernel_launch(void* const* d_in, const int* in_sizes, int n_in,
                              void* d_out, int out_size, void* d_ws, size_t ws_size,
                              hipStream_t stream) {
    const float* x  = (const float*)d_in[0];
    const float* W1 = (const float*)d_in[1];
    const float* b1 = (const float*)d_in[2];
    const float* W2 = (const float*)d_in[3];
    const float* b2 = (const float*)d_in[4];
    float* out = (float*)d_out;

    char* ws = (char*)d_ws;
    unsigned short* W1bf = (unsigned short*)ws;                    // 4 MB
    unsigned short* W2bf = (unsigned short*)(ws + (4u << 20));     // 4 MB

    const int WELEM = NB * BOUT * BIN;          // 2,097,152 per weight tensor
    cvt_f32_bf16<<<(WELEM / 4 + 255) / 256, 256, 0, stream>>>(W1, W1bf, WELEM / 4);
    cvt_f32_bf16<<<(WELEM / 4 + 255) / 256, 256, 0, stream>>>(W2, W2bf, WELEM / 4);

    const int GRID = NB * (BATCH / 128);        // 8 * 64 = 512
    fused_mlp<<<GRID, 512, 0, stream>>>(x, W1bf, b1, W2bf, b2, out);
}